// Round 12
// baseline (1759.402 us; speedup 1.0000x reference)
//
#include <hip/hip_runtime.h>
#include <stdint.h>

#define B 64
#define S 512
#define E 512
#define H 1024
#define NCLS 4

typedef __attribute__((ext_vector_type(8))) short short8;
typedef __attribute__((ext_vector_type(4))) float f32x4;

__device__ __forceinline__ unsigned short f32_to_bf16(float f) {
    unsigned int x = __float_as_uint(f);
    unsigned int r = (x + 0x7fffu + ((x >> 16) & 1u)) >> 16;   // RNE
    return (unsigned short)r;
}
__device__ __forceinline__ float bf16_to_f32(unsigned short u) {
    return __uint_as_float(((unsigned int)u) << 16);
}

// write-through store (L1+L2 bypass -> MALL coherence point). PROVEN R2-R11.
__device__ __forceinline__ void store_sc4u(unsigned int* p, unsigned int v) {
    asm volatile("global_store_dword %0, %1, off sc0 sc1"
                 :: "v"(p), "v"(v) : "memory");
}

// MALL-coherent 16B load, offset-folded immediate. =&v: never alias address.
#define LD128(dst, base, off) \
    asm volatile("global_load_dwordx4 %0, %1, off offset:" #off " sc0 sc1" \
                 : "=&v"(dst) : "v"(base) : "memory")

// ---------------------------------------------------------------------------
// K1: wx[s][b][j] = sum_k emb[x[b*S+s]][k] * W[j][k] + b_w[j], stored bf16.
// (unchanged; ~57 us)
// ---------------------------------------------------------------------------
#define K1_LDA 40

__global__ __launch_bounds__(256) void k_wx_gemm(
    const int* __restrict__ x, const float* __restrict__ emb,
    const float* __restrict__ W, const float* __restrict__ bw,
    unsigned short* __restrict__ wx)
{
    __shared__ unsigned short Asub[128 * K1_LDA];
    __shared__ unsigned short Bsub[128 * K1_LDA];

    const int t  = threadIdx.x;
    const int mt = blockIdx.x;
    const int nt = blockIdx.y;
    const int i0 = mt * 128;
    const int j0 = nt * 128;

    const int r  = t >> 1;
    const int kh = (t & 1) * 16;
    const int tok = x[i0 + r];
    const float* arow = emb + (size_t)tok * E;
    const float* brow = W + (size_t)(j0 + r) * E;

    const int lane = t & 63;
    const int w    = t >> 6;
    const int wm   = (w >> 1) * 64;
    const int wn   = (w & 1) * 64;
    const int fr   = lane & 15;
    const int kg   = lane >> 4;

    f32x4 acc[4][4] = {};

    for (int kt = 0; kt < E; kt += 32) {
        __syncthreads();
        {
            union { unsigned short us[8]; uint4 v; } p;
            const float* srcA = arow + kt + kh;
            #pragma unroll
            for (int i = 0; i < 8; ++i) p.us[i] = f32_to_bf16(srcA[i]);
            *(uint4*)&Asub[r * K1_LDA + kh] = p.v;
            #pragma unroll
            for (int i = 0; i < 8; ++i) p.us[i] = f32_to_bf16(srcA[8 + i]);
            *(uint4*)&Asub[r * K1_LDA + kh + 8] = p.v;
            const float* srcB = brow + kt + kh;
            #pragma unroll
            for (int i = 0; i < 8; ++i) p.us[i] = f32_to_bf16(srcB[i]);
            *(uint4*)&Bsub[r * K1_LDA + kh] = p.v;
            #pragma unroll
            for (int i = 0; i < 8; ++i) p.us[i] = f32_to_bf16(srcB[8 + i]);
            *(uint4*)&Bsub[r * K1_LDA + kh + 8] = p.v;
        }
        __syncthreads();

        short8 a[4], b[4];
        #pragma unroll
        for (int mi = 0; mi < 4; ++mi)
            a[mi] = *(const short8*)&Asub[(wm + mi * 16 + fr) * K1_LDA + kg * 8];
        #pragma unroll
        for (int ni = 0; ni < 4; ++ni)
            b[ni] = *(const short8*)&Bsub[(wn + ni * 16 + fr) * K1_LDA + kg * 8];
        #pragma unroll
        for (int mi = 0; mi < 4; ++mi)
            #pragma unroll
            for (int ni = 0; ni < 4; ++ni)
                acc[mi][ni] = __builtin_amdgcn_mfma_f32_16x16x32_bf16(
                                  a[mi], b[ni], acc[mi][ni], 0, 0, 0);
    }

    float bwv[4];
    #pragma unroll
    for (int ni = 0; ni < 4; ++ni) bwv[ni] = bw[j0 + wn + ni * 16 + fr];
    #pragma unroll
    for (int mi = 0; mi < 4; ++mi) {
        #pragma unroll
        for (int ni = 0; ni < 4; ++ni) {
            const int gn = j0 + wn + ni * 16 + fr;
            #pragma unroll
            for (int rr = 0; rr < 4; ++rr) {
                const int gm = i0 + wm + mi * 16 + kg * 4 + rr;
                const int bb = gm >> 9;
                const int ss = gm & 511;
                wx[(size_t)(ss * B + bb) * H + gn] =
                    f32_to_bf16(acc[mi][ni][rr] + bwv[ni]);
            }
        }
    }
}

// ---------------------------------------------------------------------------
// K2: persistent recurrence = R11 structure (1592us measured) with
// DIRECT-TO-REGISTER h staging: no LDS round-trip for H.
//  - MFMA C rows 8-15 are never read (redC stores rows 0-7 only), and C row
//    i depends only on A row i -> lanes fr>=8 need no h data at all.
//    Lanes fr<8 load their exact A-fragments (2 x dwordx4 per kk, offset-
//    folded) from MALL; hi/lo split built in-register (3 bit-ops/dword).
//  - Everything else identical to R11: wave-private 8-producer flag poll,
//    single bf16 U plane XOR-swizzled in LDS, 2 barriers/step (barD redC,
//    barE publish-drain), sc0sc1 publish + t0 flag.
//  - LDS: 64K U + 4K redC + 32K pad (keeps 1 wg/CU placement) = 100 KB.
// ---------------------------------------------------------------------------
__global__ __launch_bounds__(256) void k_rnn(
    const unsigned short* __restrict__ wx, const float* __restrict__ U,
    const float* __restrict__ Vw, const float* __restrict__ bv,
    unsigned int* __restrict__ hbuf, unsigned int* __restrict__ flags,
    float* __restrict__ out)
{
    __shared__ __align__(16) unsigned short Uhi[32 * 1024];   // 64 KB
    __shared__ __align__(16) float redC[1024];                //  4 KB
    __shared__ __align__(16) unsigned int pad_lds[8192];      // 32 KB (placement)

    const int t   = threadIdx.x;
    const int g   = blockIdx.x & 7;      // group: batches [8g, 8g+8)
    const int m   = blockIdx.x >> 3;     // member: j rows [32m, 32m+32)
    const int j0  = m * 32;
    const int bg0 = g * 8;

    ((volatile unsigned int*)pad_lds)[t] = (unsigned int)t;  // keep pad live

    // ---- stage U -> bf16 plane, swizzled (byte ^= (row&7)<<4) ----
    for (int rr = 0; rr < 32; ++rr) {
        f32x4 v = *(const f32x4*)(U + (size_t)(j0 + rr) * H + t * 4);
        uint2 hwd;
        hwd.x = f32_to_bf16(v[0]) | ((unsigned)f32_to_bf16(v[1]) << 16);
        hwd.y = f32_to_bf16(v[2]) | ((unsigned)f32_to_bf16(v[3]) << 16);
        const int byteoff = (rr * 2048 + t * 8) ^ ((rr & 7) << 4);
        *(uint2*)((char*)Uhi + byteoff) = hwd;
    }

    // role constants
    const int lane  = t & 63;
    const int w     = t >> 6;            // wave id = K-chunk (256 k each)
    const int fr    = lane & 15;
    const int kg    = lane >> 4;         // 0..3
    const int kbase = w * 256;
    const int abrow = fr & 7;            // A (h) row: only rows 0-7 matter
    const int ob    = t >> 5;            // output batch 0..7
    const int oj    = t & 31;            // output j local 0..31

    unsigned int* fl = flags + g * 32;

    float wxv = bf16_to_f32(wx[(size_t)(bg0 + ob) * H + j0 + oj]);

    __syncthreads();                     // U resident

    for (int ts = 0; ts < S; ++ts) {
        const unsigned int* hr = hbuf + (ts & 1) * (B * H);
        unsigned int*       hw = hbuf + ((ts + 1) & 1) * (B * H);

        // prefetch next step's wx (h-independent, cached) before the poll
        float wx_next = 0.f;
        if (ts + 1 < S)
            wx_next = bf16_to_f32(wx[(size_t)((ts + 1) * B + bg0 + ob) * H + j0 + oj]);

        // ---- wave-private poll: my k-chunk's 8 producers only ----
        {
            const unsigned int* fp = fl + w * 8 + (lane & 7);
            unsigned int fv;
            do {
                fv = __hip_atomic_load(fp, __ATOMIC_RELAXED,
                                       __HIP_MEMORY_SCOPE_AGENT);
            } while (!__all((int)(fv >= (unsigned)ts)));
        }

        // ---- direct-to-register A-fragment loads (lanes fr<8 only) ----
        // lane (fr,kg) needs h[bg0+abrow][k..k+8) for k = kbase+kk*32+kg*8
        uint4 hv[16];
        {
            const unsigned int* hb =
                hr + (size_t)(bg0 + abrow) * H + kbase + kg * 8;
            if (fr < 8) {
                LD128(hv[ 0], hb,   0); LD128(hv[ 1], hb,  16);
                LD128(hv[ 2], hb, 128); LD128(hv[ 3], hb, 144);
                LD128(hv[ 4], hb, 256); LD128(hv[ 5], hb, 272);
                LD128(hv[ 6], hb, 384); LD128(hv[ 7], hb, 400);
                LD128(hv[ 8], hb, 512); LD128(hv[ 9], hb, 528);
                LD128(hv[10], hb, 640); LD128(hv[11], hb, 656);
                LD128(hv[12], hb, 768); LD128(hv[13], hb, 784);
                LD128(hv[14], hb, 896); LD128(hv[15], hb, 912);
            }
            asm volatile("s_waitcnt vmcnt(0)" ::: "memory");
            __builtin_amdgcn_sched_barrier(0);
        }

        // ---- MFMA: C[16b x 32j] over my k-chunk, 2 split terms ----
        f32x4 acc0 = {}, acc1 = {};
        #pragma unroll
        for (int kk = 0; kk < 8; ++kk) {
            const uint4 pa = hv[2 * kk], pb = hv[2 * kk + 1];
            const unsigned int wj[8] = {pa.x, pa.y, pa.z, pa.w,
                                        pb.x, pb.y, pb.z, pb.w};
            union { unsigned int u[4]; short8 s; } Ahi, Alo;
            #pragma unroll
            for (int i = 0; i < 4; ++i) {
                Ahi.u[i] = (wj[2*i+1] & 0xffff0000u) | (wj[2*i] >> 16);
                Alo.u[i] = (wj[2*i+1] << 16) | (wj[2*i] & 0xffffu);
            }
            const int k  = kbase + kk * 32 + kg * 8;
            const int b0 = (fr * 2048 + k * 2) ^ ((fr & 7) << 4);
            const int b1 = ((16 + fr) * 2048 + k * 2) ^ ((fr & 7) << 4);
            const short8 bh0 = *(const short8*)((const char*)Uhi + b0);
            const short8 bh1 = *(const short8*)((const char*)Uhi + b1);
            acc0 = __builtin_amdgcn_mfma_f32_16x16x32_bf16(Ahi.s, bh0, acc0, 0, 0, 0);
            acc0 = __builtin_amdgcn_mfma_f32_16x16x32_bf16(Alo.s, bh0, acc0, 0, 0, 0);
            acc1 = __builtin_amdgcn_mfma_f32_16x16x32_bf16(Ahi.s, bh1, acc1, 0, 0, 0);
            acc1 = __builtin_amdgcn_mfma_f32_16x16x32_bf16(Alo.s, bh1, acc1, 0, 0, 0);
        }

        // ---- per-wave partial-C into redC ----
        if (kg < 2) {
            #pragma unroll
            for (int rr = 0; rr < 4; ++rr) {
                const int mb = kg * 4 + rr;          // batch row 0..7
                redC[w * 256 + mb * 32 + fr]      = acc0[rr];
                redC[w * 256 + mb * 32 + 16 + fr] = acc1[rr];
            }
        }
        __syncthreads();                 // barD: redC complete

        float sum = redC[      ob * 32 + oj] + redC[256 + ob * 32 + oj]
                  + redC[512 + ob * 32 + oj] + redC[768 + ob * 32 + oj];

        float p = wxv + sum;
        p = fminf(fmaxf(p, -15.f), 15.f);
        const float e  = __expf(2.0f * p);
        const float hv2 = 1.0f - 2.0f / (e + 1.0f);

        // pack hi|lo and publish via write-through store
        const unsigned short hib = f32_to_bf16(hv2);
        const unsigned short lob = f32_to_bf16(hv2 - bf16_to_f32(hib));
        store_sc4u(hw + (size_t)(bg0 + ob) * H + j0 + oj,
                   ((unsigned int)hib << 16) | lob);
        asm volatile("s_waitcnt vmcnt(0)" ::: "memory");
        __syncthreads();                 // barE: all waves' h stores at MALL
        if (t == 0)
            __hip_atomic_store(&fl[m], (unsigned)(ts + 1), __ATOMIC_RELAXED,
                               __HIP_MEMORY_SCOPE_AGENT);
        wxv = wx_next;
    }

    // ---- final projection: out[b][c] = h_final[b] . V[c] + bv[c] ----
    if (m == 0) {
        if (t < 32)
            while (__hip_atomic_load(&fl[t], __ATOMIC_RELAXED,
                                     __HIP_MEMORY_SCOPE_AGENT) < (unsigned)S) {}
        __syncthreads();
        const unsigned int* hf = hbuf;   // S even -> final state in buf0
        const int o = t & 31, part = t >> 5;
        const int pb = o >> 2, c = o & 3;
        const unsigned long long* hrow =
            (const unsigned long long*)(hf + (size_t)(bg0 + pb) * H) + part * 64;
        const float* vrow = Vw + (size_t)c * H + part * 128;
        float partial = 0.f;
        for (int q = 0; q < 64; ++q) {
            unsigned long long vvq = __hip_atomic_load(hrow + q, __ATOMIC_RELAXED,
                                                       __HIP_MEMORY_SCOPE_AGENT);
            const unsigned int v0 = (unsigned int)vvq;
            const unsigned int v1 = (unsigned int)(vvq >> 32);
            const float h0 = bf16_to_f32((unsigned short)(v0 >> 16))
                           + bf16_to_f32((unsigned short)(v0 & 0xffffu));
            const float h1 = bf16_to_f32((unsigned short)(v1 >> 16))
                           + bf16_to_f32((unsigned short)(v1 & 0xffffu));
            partial += h0 * vrow[2 * q] + h1 * vrow[2 * q + 1];
        }
        __syncthreads();
        redC[part * 32 + o] = partial;
        __syncthreads();
        if (t < 32) {
            float sv = 0.f;
            #pragma unroll
            for (int pq = 0; pq < 8; ++pq) sv += redC[pq * 32 + t];
            out[(bg0 + (t >> 2)) * NCLS + (t & 3)] = sv + bv[t & 3];
        }
    }
}

// ---------------------------------------------------------------------------
extern "C" void kernel_launch(void* const* d_in, const int* in_sizes, int n_in,
                              void* d_out, int out_size, void* d_ws, size_t ws_size,
                              hipStream_t stream)
{
    const int*   x   = (const int*)d_in[0];
    const float* emb = (const float*)d_in[1];
    const float* W   = (const float*)d_in[2];
    const float* bw  = (const float*)d_in[3];
    const float* U   = (const float*)d_in[4];
    const float* V   = (const float*)d_in[5];
    const float* bv  = (const float*)d_in[6];
    float* out = (float*)d_out;

    unsigned short* wx = (unsigned short*)d_ws;
    const size_t WX_BYTES = (size_t)S * B * H * sizeof(unsigned short); // 64 MiB
    unsigned int* hbuf = (unsigned int*)((char*)d_ws + WX_BYTES);
    const size_t HB_BYTES = (size_t)2 * B * H * sizeof(unsigned int);   // 512 KiB
    unsigned int* flags = (unsigned int*)((char*)d_ws + WX_BYTES + HB_BYTES);

    // zero h double-buffer (h0 = 0) + 8x32 member flags
    hipMemsetAsync((char*)d_ws + WX_BYTES, 0, HB_BYTES + 2048, stream);

    hipLaunchKernelGGL(k_wx_gemm, dim3(256, 8), dim3(256), 0, stream,
                       x, emb, W, bw, wx);
    hipLaunchKernelGGL(k_rnn, dim3(256), dim3(256), 0, stream,
                       wx, U, V, bv, hbuf, flags, out);
}

// Round 13
// 1557.113 us; speedup vs baseline: 1.1299x; 1.1299x over previous
//
#include <hip/hip_runtime.h>
#include <stdint.h>

#define B 64
#define S 512
#define E 512
#define H 1024
#define NCLS 4

typedef __attribute__((ext_vector_type(8))) short short8;
typedef __attribute__((ext_vector_type(4))) float f32x4;

__device__ __forceinline__ unsigned short f32_to_bf16(float f) {
    unsigned int x = __float_as_uint(f);
    unsigned int r = (x + 0x7fffu + ((x >> 16) & 1u)) >> 16;   // RNE
    return (unsigned short)r;
}
__device__ __forceinline__ float bf16_to_f32(unsigned short u) {
    return __uint_as_float(((unsigned int)u) << 16);
}

// write-through store (L1+L2 bypass -> MALL coherence point). PROVEN R2-R12.
__device__ __forceinline__ void store_sc4u(unsigned int* p, unsigned int v) {
    asm volatile("global_store_dword %0, %1, off sc0 sc1"
                 :: "v"(p), "v"(v) : "memory");
}

// ---------------------------------------------------------------------------
// K1: wx[s][b][j] = sum_k emb[x[b*S+s]][k] * W[j][k] + b_w[j], stored bf16.
// (unchanged; ~57 us)
// ---------------------------------------------------------------------------
#define K1_LDA 40

__global__ __launch_bounds__(256) void k_wx_gemm(
    const int* __restrict__ x, const float* __restrict__ emb,
    const float* __restrict__ W, const float* __restrict__ bw,
    unsigned short* __restrict__ wx)
{
    __shared__ unsigned short Asub[128 * K1_LDA];
    __shared__ unsigned short Bsub[128 * K1_LDA];

    const int t  = threadIdx.x;
    const int mt = blockIdx.x;
    const int nt = blockIdx.y;
    const int i0 = mt * 128;
    const int j0 = nt * 128;

    const int r  = t >> 1;
    const int kh = (t & 1) * 16;
    const int tok = x[i0 + r];
    const float* arow = emb + (size_t)tok * E;
    const float* brow = W + (size_t)(j0 + r) * E;

    const int lane = t & 63;
    const int w    = t >> 6;
    const int wm   = (w >> 1) * 64;
    const int wn   = (w & 1) * 64;
    const int fr   = lane & 15;
    const int kg   = lane >> 4;

    f32x4 acc[4][4] = {};

    for (int kt = 0; kt < E; kt += 32) {
        __syncthreads();
        {
            union { unsigned short us[8]; uint4 v; } p;
            const float* srcA = arow + kt + kh;
            #pragma unroll
            for (int i = 0; i < 8; ++i) p.us[i] = f32_to_bf16(srcA[i]);
            *(uint4*)&Asub[r * K1_LDA + kh] = p.v;
            #pragma unroll
            for (int i = 0; i < 8; ++i) p.us[i] = f32_to_bf16(srcA[8 + i]);
            *(uint4*)&Asub[r * K1_LDA + kh + 8] = p.v;
            const float* srcB = brow + kt + kh;
            #pragma unroll
            for (int i = 0; i < 8; ++i) p.us[i] = f32_to_bf16(srcB[i]);
            *(uint4*)&Bsub[r * K1_LDA + kh] = p.v;
            #pragma unroll
            for (int i = 0; i < 8; ++i) p.us[i] = f32_to_bf16(srcB[8 + i]);
            *(uint4*)&Bsub[r * K1_LDA + kh + 8] = p.v;
        }
        __syncthreads();

        short8 a[4], b[4];
        #pragma unroll
        for (int mi = 0; mi < 4; ++mi)
            a[mi] = *(const short8*)&Asub[(wm + mi * 16 + fr) * K1_LDA + kg * 8];
        #pragma unroll
        for (int ni = 0; ni < 4; ++ni)
            b[ni] = *(const short8*)&Bsub[(wn + ni * 16 + fr) * K1_LDA + kg * 8];
        #pragma unroll
        for (int mi = 0; mi < 4; ++mi)
            #pragma unroll
            for (int ni = 0; ni < 4; ++ni)
                acc[mi][ni] = __builtin_amdgcn_mfma_f32_16x16x32_bf16(
                                  a[mi], b[ni], acc[mi][ni], 0, 0, 0);
    }

    float bwv[4];
    #pragma unroll
    for (int ni = 0; ni < 4; ++ni) bwv[ni] = bw[j0 + wn + ni * 16 + fr];
    #pragma unroll
    for (int mi = 0; mi < 4; ++mi) {
        #pragma unroll
        for (int ni = 0; ni < 4; ++ni) {
            const int gn = j0 + wn + ni * 16 + fr;
            #pragma unroll
            for (int rr = 0; rr < 4; ++rr) {
                const int gm = i0 + wm + mi * 16 + kg * 4 + rr;
                const int bb = gm >> 9;
                const int ss = gm & 511;
                wx[(size_t)(ss * B + bb) * H + gn] =
                    f32_to_bf16(acc[mi][ni][rr] + bwv[ni]);
            }
        }
    }
}

// ---------------------------------------------------------------------------
// K2: persistent recurrence = R11 structure (1592us measured) with
// PER-(MEMBER,WAVE) FLAGS: barE removed; each wave drains its own h stores
// (wave-local vmcnt) and sets flag[m*4+w]. Consumer wave w polls its 8
// producers x 4 waves = 32 flags (one 128B line, lane-parallel).
//  - WAR: flag[Y][w']>=ts  =>  Y passed barD(ts-1)  =>  (syncthreads) all
//    Y waves finished reading buf[(ts-1)&1]. X writes h(ts+1) after barD(ts)
//    which joins polls covering all 32 members x 4 waves.
//  - redC double-buffered (ts&1): write(ts+2) gated by barD(ts+1), after
//    all sum-reads(ts) -> safe without barE.
//  - One barrier per step (barD).
//  - LDS: 64K U + 16K Hhi + 16K Hlo + 8K redC = 104 KB (1 wg/CU).
// ---------------------------------------------------------------------------
__global__ __launch_bounds__(256) void k_rnn(
    const unsigned short* __restrict__ wx, const float* __restrict__ U,
    const float* __restrict__ Vw, const float* __restrict__ bv,
    unsigned int* __restrict__ hbuf, unsigned int* __restrict__ flags,
    float* __restrict__ out)
{
    __shared__ __align__(16) unsigned short Uhi[32 * 1024];   // 64 KB
    __shared__ __align__(16) unsigned int Hh32[8 * 512];      // 16 KB
    __shared__ __align__(16) unsigned int Hl32[8 * 512];      // 16 KB
    __shared__ __align__(16) float redC[2][1024];             //  8 KB

    const int t   = threadIdx.x;
    const int g   = blockIdx.x & 7;      // group: batches [8g, 8g+8)
    const int m   = blockIdx.x >> 3;     // member: j rows [32m, 32m+32)
    const int j0  = m * 32;
    const int bg0 = g * 8;

    // ---- stage U -> bf16 plane, swizzled (byte ^= (row&7)<<4) ----
    for (int rr = 0; rr < 32; ++rr) {
        f32x4 v = *(const f32x4*)(U + (size_t)(j0 + rr) * H + t * 4);
        uint2 hwd;
        hwd.x = f32_to_bf16(v[0]) | ((unsigned)f32_to_bf16(v[1]) << 16);
        hwd.y = f32_to_bf16(v[2]) | ((unsigned)f32_to_bf16(v[3]) << 16);
        const int byteoff = (rr * 2048 + t * 8) ^ ((rr & 7) << 4);
        *(uint2*)((char*)Uhi + byteoff) = hwd;
    }

    // role constants
    const int lane  = t & 63;
    const int w     = t >> 6;            // wave id = K-chunk (256 k each)
    const int fr    = lane & 15;
    const int kg    = lane >> 4;         // 0..3
    const int kbase = w * 256;
    const int abrow = fr & 7;            // A (h) row: batches 8-15 dup 0-7
    const int ob    = t >> 5;            // output batch 0..7
    const int oj    = t & 31;            // output j local 0..31

    unsigned int* fl = flags + g * 128;  // [member][wave] flags

    float wxv = bf16_to_f32(wx[(size_t)(bg0 + ob) * H + j0 + oj]);

    __syncthreads();                     // U resident

    for (int ts = 0; ts < S; ++ts) {
        const unsigned int* hr = hbuf + (ts & 1) * (B * H);
        unsigned int*       hw = hbuf + ((ts + 1) & 1) * (B * H);

        // prefetch next step's wx (h-independent, cached) before the poll
        float wx_next = 0.f;
        if (ts + 1 < S)
            wx_next = bf16_to_f32(wx[(size_t)((ts + 1) * B + bg0 + ob) * H + j0 + oj]);

        // ---- wave-private poll: 8 producers x 4 waves = 32 contiguous flags
        {
            const unsigned int* fp = fl + w * 32 + (lane & 31);
            unsigned int fv;
            do {
                fv = __hip_atomic_load(fp, __ATOMIC_RELAXED,
                                       __HIP_MEMORY_SCOPE_AGENT);
            } while (!__all((int)(fv >= (unsigned)ts)));
        }

        // ---- wave-private stage: k-chunk [256w,256w+256) x 8 batches ----
        // lane covers 16 u64 words: li = lane + 64*i -> b = li>>7, col = li&127
        {
            const unsigned long long* hb64 = (const unsigned long long*)hr;
            unsigned long long vv[16];
            #pragma unroll
            for (int i = 0; i < 16; ++i) {
                const int li = lane + 64 * i;
                const int b = li >> 7, col = li & 127;
                vv[i] = __hip_atomic_load(
                    hb64 + (size_t)(bg0 + b) * 512 + w * 128 + col,
                    __ATOMIC_RELAXED, __HIP_MEMORY_SCOPE_AGENT);
            }
            #pragma unroll
            for (int i = 0; i < 16; ++i) {
                const int li = lane + 64 * i;
                const int b = li >> 7;
                const int k2 = w * 128 + (li & 127);
                const unsigned int v0 = (unsigned int)vv[i];
                const unsigned int v1 = (unsigned int)(vv[i] >> 32);
                const int idx = (b * 512 + k2) ^ (b << 2);
                Hh32[idx] = (v0 >> 16) | (v1 & 0xffff0000u);
                Hl32[idx] = (v0 & 0xffffu) | (v1 << 16);
            }
        }
        // no barrier: wave w's MFMA reads only its own staged k-chunk

        // ---- MFMA: C[16b x 32j] over my k-chunk, 2 split terms ----
        f32x4 acc0 = {}, acc1 = {};
        #pragma unroll
        for (int kk = 0; kk < 8; ++kk) {
            const int k  = kbase + kk * 32 + kg * 8;
            const int ab = (abrow * 2048 + k * 2) ^ (abrow << 4);
            const short8 ahi = *(const short8*)((const char*)Hh32 + ab);
            const short8 alo = *(const short8*)((const char*)Hl32 + ab);
            const int b0 = (fr * 2048 + k * 2) ^ ((fr & 7) << 4);
            const int b1 = ((16 + fr) * 2048 + k * 2) ^ ((fr & 7) << 4);
            const short8 bh0 = *(const short8*)((const char*)Uhi + b0);
            const short8 bh1 = *(const short8*)((const char*)Uhi + b1);
            acc0 = __builtin_amdgcn_mfma_f32_16x16x32_bf16(ahi, bh0, acc0, 0, 0, 0);
            acc0 = __builtin_amdgcn_mfma_f32_16x16x32_bf16(alo, bh0, acc0, 0, 0, 0);
            acc1 = __builtin_amdgcn_mfma_f32_16x16x32_bf16(ahi, bh1, acc1, 0, 0, 0);
            acc1 = __builtin_amdgcn_mfma_f32_16x16x32_bf16(alo, bh1, acc1, 0, 0, 0);
        }

        // ---- per-wave partial-C into double-buffered redC ----
        float* rc = redC[ts & 1];
        if (kg < 2) {
            #pragma unroll
            for (int rr = 0; rr < 4; ++rr) {
                const int mb = kg * 4 + rr;          // batch row 0..7
                rc[w * 256 + mb * 32 + fr]      = acc0[rr];
                rc[w * 256 + mb * 32 + 16 + fr] = acc1[rr];
            }
        }
        __syncthreads();                 // barD: redC complete (the one barrier)

        float sum = rc[      ob * 32 + oj] + rc[256 + ob * 32 + oj]
                  + rc[512 + ob * 32 + oj] + rc[768 + ob * 32 + oj];

        float p = wxv + sum;
        p = fminf(fmaxf(p, -15.f), 15.f);
        const float e  = __expf(2.0f * p);
        const float hv = 1.0f - 2.0f / (e + 1.0f);

        // pack hi|lo, publish, wave-local drain, per-wave flag
        const unsigned short hib = f32_to_bf16(hv);
        const unsigned short lob = f32_to_bf16(hv - bf16_to_f32(hib));
        store_sc4u(hw + (size_t)(bg0 + ob) * H + j0 + oj,
                   ((unsigned int)hib << 16) | lob);
        asm volatile("s_waitcnt vmcnt(0)" ::: "memory");   // this wave's h at MALL
        if (lane == 0)
            __hip_atomic_store(&fl[m * 4 + w], (unsigned)(ts + 1),
                               __ATOMIC_RELAXED, __HIP_MEMORY_SCOPE_AGENT);
        wxv = wx_next;
    }

    // ---- final projection: out[b][c] = h_final[b] . V[c] + bv[c] ----
    if (m == 0) {
        if (t < 128)
            while (__hip_atomic_load(&fl[t], __ATOMIC_RELAXED,
                                     __HIP_MEMORY_SCOPE_AGENT) < (unsigned)S) {}
        __syncthreads();
        const unsigned int* hf = hbuf;   // S even -> final state in buf0
        const int o = t & 31, part = t >> 5;
        const int pb = o >> 2, c = o & 3;
        const unsigned long long* hrow =
            (const unsigned long long*)(hf + (size_t)(bg0 + pb) * H) + part * 64;
        const float* vrow = Vw + (size_t)c * H + part * 128;
        float partial = 0.f;
        for (int q = 0; q < 64; ++q) {
            unsigned long long vvq = __hip_atomic_load(hrow + q, __ATOMIC_RELAXED,
                                                       __HIP_MEMORY_SCOPE_AGENT);
            const unsigned int v0 = (unsigned int)vvq;
            const unsigned int v1 = (unsigned int)(vvq >> 32);
            const float h0 = bf16_to_f32((unsigned short)(v0 >> 16))
                           + bf16_to_f32((unsigned short)(v0 & 0xffffu));
            const float h1 = bf16_to_f32((unsigned short)(v1 >> 16))
                           + bf16_to_f32((unsigned short)(v1 & 0xffffu));
            partial += h0 * vrow[2 * q] + h1 * vrow[2 * q + 1];
        }
        __syncthreads();
        redC[0][part * 32 + o] = partial;
        __syncthreads();
        if (t < 32) {
            float sv = 0.f;
            #pragma unroll
            for (int pq = 0; pq < 8; ++pq) sv += redC[0][pq * 32 + t];
            out[(bg0 + (t >> 2)) * NCLS + (t & 3)] = sv + bv[t & 3];
        }
    }
}

// ---------------------------------------------------------------------------
extern "C" void kernel_launch(void* const* d_in, const int* in_sizes, int n_in,
                              void* d_out, int out_size, void* d_ws, size_t ws_size,
                              hipStream_t stream)
{
    const int*   x   = (const int*)d_in[0];
    const float* emb = (const float*)d_in[1];
    const float* W   = (const float*)d_in[2];
    const float* bw  = (const float*)d_in[3];
    const float* U   = (const float*)d_in[4];
    const float* V   = (const float*)d_in[5];
    const float* bv  = (const float*)d_in[6];
    float* out = (float*)d_out;

    unsigned short* wx = (unsigned short*)d_ws;
    const size_t WX_BYTES = (size_t)S * B * H * sizeof(unsigned short); // 64 MiB
    unsigned int* hbuf = (unsigned int*)((char*)d_ws + WX_BYTES);
    const size_t HB_BYTES = (size_t)2 * B * H * sizeof(unsigned int);   // 512 KiB
    unsigned int* flags = (unsigned int*)((char*)d_ws + WX_BYTES + HB_BYTES);

    // zero h double-buffer (h0 = 0) + 8x128 per-(member,wave) flags
    hipMemsetAsync((char*)d_ws + WX_BYTES, 0, HB_BYTES + 8192, stream);

    hipLaunchKernelGGL(k_wx_gemm, dim3(256, 8), dim3(256), 0, stream,
                       x, emb, W, bw, wx);
    hipLaunchKernelGGL(k_rnn, dim3(256), dim3(256), 0, stream,
                       wx, U, V, bv, hbuf, flags, out);
}